// Round 3
// baseline (125.478 us; speedup 1.0000x reference)
//
#include <hip/hip_runtime.h>
#include <stdint.h>

// SupConLossWithPrototype on MI355X.
// Round 14: k_sym is latency-bound with all pipes <15% (9 schedule variants,
// 44-53us regardless of work) -> its VALU is free. Exploit that:
//  - k_sym now accumulates BOTH exp2(D) and raw D per element (novel-masked),
//    with exact in-tile diagonal exclusion on the 64 diagonal blocks
//    (uniform-branch template path). This deletes the entire g/gpart/zcol
//    column-sum machinery and k_final's sZ/dd dot products (and its Fb/Fc
//    reads). +2 FMA/elem in a 12%-busy kernel.
//  - per-iteration dependent nf[] load + i2f hoisted to prologue (nmcA[16]).
//  - k_prep: conversion + proto-MFMA + nf only.
//  - k_final: 8 slot loads + shfl + scalar math per row. Numerically cleaner
//    (no exp2(dd) subtraction).

#define M_TOT 8192
#define K_DIM 128
#define B_PRO 100
#define INV_T 5.0f                          // 1/TEMP
#define C_SCALE 7.2134752044448170f         // 5 * log2(e)
#define LN2    0.6931471805599453f
#define RT    256                           // k_sym tile side
#define NT    (M_TOT / RT)                  // 32 row/col groups
#define NDIAG (2 * NT)                      // 64 diagonal half-blocks
#define NPAIR (NT * (NT - 1) / 2)           // 496 strict upper pairs
#define NBLK  (NDIAG + 2 * NPAIR)           // 1056 blocks
#define PB    112                           // padded proto rows (7 groups of 16)
#define PS    136                           // proto LDS stride (bf16 elems)
#define FS    136                           // feat LDS stride

#if __has_builtin(__builtin_amdgcn_exp2f)
#define EXP2(x) __builtin_amdgcn_exp2f(x)
#else
#define EXP2(x) __expf((x) * 0.6931471805599453f)
#endif

typedef __attribute__((ext_vector_type(8))) short  short8;   // 8 bf16 (MFMA A/B frag)
typedef __attribute__((ext_vector_type(4))) float  floatx4;  // MFMA C/D frag

__device__ __forceinline__ float bf2f(unsigned short u) {
    union { unsigned int i; float f; } v; v.i = ((unsigned int)u) << 16; return v.f;
}
__device__ __forceinline__ unsigned short f2bf(float x) {   // RNE
    union { float f; unsigned int i; } v; v.f = x;
    return (unsigned short)((v.i + 0x7fffu + ((v.i >> 16) & 1u)) >> 16);
}
__device__ __forceinline__ float lo_bf(unsigned int u) {
    union { unsigned int i; float f; } v; v.i = u << 16; return v.f;
}
__device__ __forceinline__ float hi_bf(unsigned int u) {
    union { unsigned int i; float f; } v; v.i = u & 0xffff0000u; return v.f;
}

// ---------------------------------------------------------------- k_prep
// 512 blocks x 256 thr; 16 feature rows per block.
//  - nf from labels x plabels; Fb = bf16(f); Fc = bf16(C*f) (unmasked)
//  - proto logits P via MFMA on a zero-padded 112-col proto tile
//  - zeroes its slices of rowE/rowS (k_sym only writes "live" slots)
__global__ __launch_bounds__(256) void k_prep(
        const float* __restrict__ feat, const int* __restrict__ labels,
        const float* __restrict__ protos, const int* __restrict__ plabels,
        float* __restrict__ Psum, float* __restrict__ expPsum,
        float* __restrict__ PLab, int* __restrict__ nf,
        int* __restrict__ nfcnt,
        unsigned short* __restrict__ Fb, unsigned short* __restrict__ Fc,
        float* __restrict__ rowE, float* __restrict__ rowS,
        float* __restrict__ out) {
    __shared__ unsigned short protoB[PB * PS];   // 30464 B
    __shared__ unsigned short featB[16 * FS];    // 4352 B
    __shared__ float psW[4][16], esW[4][16], plW[4][16];
    __shared__ int labL[16];
    __shared__ int plabL[B_PRO];
    __shared__ int novL[16];

    const int tid = threadIdx.x;
    const int rowBase = blockIdx.x * 16;

    if (blockIdx.x == 0 && tid == 0) out[0] = 0.f;   // k_final accumulates later

    // zero this block's slices of rowE/rowS (2 MB each total)
    {
        floatx4 z4 = (floatx4){0.f, 0.f, 0.f, 0.f};
        ((floatx4*)rowE)[blockIdx.x * 256 + tid] = z4;
        ((floatx4*)rowS)[blockIdx.x * 256 + tid] = z4;
    }

    if (tid < B_PRO) plabL[tid] = plabels[tid];
    if (tid >= 128 && tid < 144) labL[tid - 128] = labels[rowBase + tid - 128];

    // stage protos -> bf16 LDS (3200 float4s strided over 256 threads)
    for (int idx = tid; idx < 3200; idx += 256) {
        const int pr = idx >> 5, sg = idx & 31;
        float4 v = ((const float4*)protos)[idx];
        *(ushort4*)&protoB[pr * PS + sg * 4] =
            make_ushort4(f2bf(v.x), f2bf(v.y), f2bf(v.z), f2bf(v.w));
    }
    for (int idx = tid; idx < 12 * 32; idx += 256) {   // zero-pad rows 100..111
        const int pr = B_PRO + (idx >> 5), sg = idx & 31;
        *(ushort4*)&protoB[pr * PS + sg * 4] = make_ushort4(0, 0, 0, 0);
    }

    // stage this thread's feat segment (row rp, cols pq*8..+7) -> LDS + Fb + Fc
    const int rp = tid >> 4, pq = tid & 15;
    {
        const float* src = feat + (size_t)(rowBase + rp) * K_DIM + pq * 8;
        float4 fa  = ((const float4*)src)[0];
        float4 fb4 = ((const float4*)src)[1];
        ushort4 o0 = make_ushort4(f2bf(fa.x), f2bf(fa.y), f2bf(fa.z), f2bf(fa.w));
        ushort4 o1 = make_ushort4(f2bf(fb4.x), f2bf(fb4.y), f2bf(fb4.z), f2bf(fb4.w));
        *(ushort4*)&featB[rp * FS + pq * 8]     = o0;
        *(ushort4*)&featB[rp * FS + pq * 8 + 4] = o1;
        unsigned short* fbd = Fb + (size_t)(rowBase + rp) * K_DIM + pq * 8;
        *(ushort4*)&fbd[0] = o0;
        *(ushort4*)&fbd[4] = o1;
        ushort4 s0 = make_ushort4(f2bf(fa.x*C_SCALE), f2bf(fa.y*C_SCALE),
                                  f2bf(fa.z*C_SCALE), f2bf(fa.w*C_SCALE));
        ushort4 s1 = make_ushort4(f2bf(fb4.x*C_SCALE), f2bf(fb4.y*C_SCALE),
                                  f2bf(fb4.z*C_SCALE), f2bf(fb4.w*C_SCALE));
        unsigned short* fcd = Fc + (size_t)(rowBase + rp) * K_DIM + pq * 8;
        *(ushort4*)&fcd[0] = s0;
        *(ushort4*)&fcd[4] = s1;
    }
    __syncthreads();

    // novelty from the label test: nf[i] = !(labels[i] in plabels)
    const int lbl = labL[rp];
    float flg = 0.f;
    #pragma unroll
    for (int j = 0; j < 7; ++j) {
        const int jj = pq + 16 * j;
        if (jj < B_PRO && plabL[jj] == lbl) flg = 1.f;
    }
    for (int off = 1; off < 16; off <<= 1) flg += __shfl_xor(flg, off);
    if (pq == 0) {
        const int nv = (flg == 0.f) ? 1 : 0;
        nf[rowBase + rp] = nv;
        novL[rp] = nv;
    }

    // proto GEMM via MFMA: wave w handles col-group w (and w+4 if w<3)
    const int wv = tid >> 6, lane = tid & 63, quad = lane >> 4, cq = lane & 15;
    short8 af[4];
    #pragma unroll
    for (int ks = 0; ks < 4; ++ks)
        af[ks] = *(const short8*)&featB[cq * FS + ks * 32 + quad * 8];

    float ps_[4] = {0.f, 0.f, 0.f, 0.f};
    float es_[4] = {0.f, 0.f, 0.f, 0.f};
    float pl_[4] = {0.f, 0.f, 0.f, 0.f};

    #pragma unroll
    for (int gi = 0; gi < 2; ++gi) {
        const int g = wv + 4 * gi;
        if (gi == 1 && wv >= 3) break;     // groups 0..6 only
        short8 bf[4];
        #pragma unroll
        for (int ks = 0; ks < 4; ++ks)
            bf[ks] = *(const short8*)&protoB[(g * 16 + cq) * PS + ks * 32 + quad * 8];
        floatx4 D = (floatx4){0.f, 0.f, 0.f, 0.f};
        D = __builtin_amdgcn_mfma_f32_16x16x32_bf16(af[0], bf[0], D, 0, 0, 0);
        D = __builtin_amdgcn_mfma_f32_16x16x32_bf16(af[1], bf[1], D, 0, 0, 0);
        D = __builtin_amdgcn_mfma_f32_16x16x32_bf16(af[2], bf[2], D, 0, 0, 0);
        D = __builtin_amdgcn_mfma_f32_16x16x32_bf16(af[3], bf[3], D, 0, 0, 0);
        #pragma unroll
        for (int r = 0; r < 4; ++r) {
            const int bcol = g * 16 + cq;
            if (bcol < B_PRO) {
                const float Pv = D[r] * INV_T;
                ps_[r] += Pv;
                es_[r] += __expf(Pv);
                if (bcol == labL[quad * 4 + r]) pl_[r] += Pv;
            }
        }
    }
    #pragma unroll
    for (int r = 0; r < 4; ++r) {
        for (int off = 1; off < 16; off <<= 1) {
            ps_[r] += __shfl_xor(ps_[r], off);
            es_[r] += __shfl_xor(es_[r], off);
            pl_[r] += __shfl_xor(pl_[r], off);
        }
        if (cq == 0) {
            psW[wv][quad * 4 + r] = ps_[r];
            esW[wv][quad * 4 + r] = es_[r];
            plW[wv][quad * 4 + r] = pl_[r];
        }
    }
    __syncthreads();

    if (tid < 16) {
        const int i = rowBase + tid;
        Psum[i]    = psW[0][tid] + psW[1][tid] + psW[2][tid] + psW[3][tid];
        expPsum[i] = esW[0][tid] + esW[1][tid] + esW[2][tid] + esW[3][tid];
        PLab[i]    = plW[0][tid] + plW[1][tid] + plW[2][tid] + plW[3][tid];
    }
    if (tid == 255) {
        int c = 0;
        #pragma unroll
        for (int r = 0; r < 16; ++r) c += novL[r];
        nfcnt[blockIdx.x] = c;                     // non-atomic partial
    }
}

// ---------------------------------------------------------------- k_sym body
// One 128-row x 256-col half-tile. Dual accumulation: accE = sum exp2(D)*mask,
// accS = sum D*mask, both row- and col-direction. DIAG blocks exclude the
// row==col element exactly in-tile.
template<bool DIAG>
__device__ __forceinline__ void sym_body(
        int a, int b, int h, int R0, int C0,
        const unsigned short* __restrict__ Fb, const unsigned short* __restrict__ Fc,
        const int* __restrict__ nf,
        float* __restrict__ rowE, float* __restrict__ rowS,
        float (*colE)[256], float (*colS)[256]) {
    const int tid = threadIdx.x;
    const int wv = tid >> 6, lane = tid & 63;
    const int quad = lane >> 4, cq = lane & 15;

    // A fragments: rows R0 + wv*32 + mt*16 + cq, k = ks*32 + quad*8 .. +7
    short8 afr[2][4];
    #pragma unroll
    for (int mt = 0; mt < 2; ++mt)
        #pragma unroll
        for (int ks = 0; ks < 4; ++ks)
            afr[mt][ks] = *(const short8*)(Fb
                + (size_t)(R0 + wv * 32 + mt * 16 + cq) * K_DIM + ks * 32 + quad * 8);

    // row novelty masks for this lane's 8 D-rows
    float nmR[2][4];
    #pragma unroll
    for (int mt = 0; mt < 2; ++mt)
        #pragma unroll
        for (int r = 0; r < 4; ++r)
            nmR[mt][r] = (float)nf[R0 + wv * 32 + mt * 16 + quad * 4 + r];

    // col novelty, hoisted (kills per-iter dependent load + i2f)
    float nmcA[16];
    #pragma unroll
    for (int c2 = 0; c2 < 16; ++c2)
        nmcA[c2] = (float)nf[C0 + c2 * 16 + cq];

    float accE[2][4], accS[2][4];
    #pragma unroll
    for (int mt = 0; mt < 2; ++mt)
        #pragma unroll
        for (int r = 0; r < 4; ++r) { accE[mt][r] = 0.f; accS[mt][r] = 0.f; }

    const int rbase = R0 + wv * 32 + quad * 4;   // DIAG row index helper

    // B fragments for ct=0, 1-deep rotation
    const unsigned short* bb = Fc + (size_t)(C0 + cq) * K_DIM + quad * 8;
    short8 b0 = *(const short8*)(bb);
    short8 b1 = *(const short8*)(bb + 32);
    short8 b2 = *(const short8*)(bb + 64);
    short8 b3 = *(const short8*)(bb + 96);

    #pragma unroll 1
    for (int ct = 0; ct < 16; ++ct) {
        const int nx = (ct < 15) ? ct + 1 : ct;   // last iter: reload same (unused)
        const unsigned short* nb = Fc + (size_t)(C0 + nx * 16 + cq) * K_DIM + quad * 8;
        short8 t0 = *(const short8*)(nb);
        short8 t1 = *(const short8*)(nb + 32);
        short8 t2 = *(const short8*)(nb + 64);
        short8 t3 = *(const short8*)(nb + 96);

        floatx4 D0 = (floatx4){0.f, 0.f, 0.f, 0.f};
        floatx4 D1 = (floatx4){0.f, 0.f, 0.f, 0.f};
        D0 = __builtin_amdgcn_mfma_f32_16x16x32_bf16(afr[0][0], b0, D0, 0, 0, 0);
        D0 = __builtin_amdgcn_mfma_f32_16x16x32_bf16(afr[0][1], b1, D0, 0, 0, 0);
        D0 = __builtin_amdgcn_mfma_f32_16x16x32_bf16(afr[0][2], b2, D0, 0, 0, 0);
        D0 = __builtin_amdgcn_mfma_f32_16x16x32_bf16(afr[0][3], b3, D0, 0, 0, 0);
        D1 = __builtin_amdgcn_mfma_f32_16x16x32_bf16(afr[1][0], b0, D1, 0, 0, 0);
        D1 = __builtin_amdgcn_mfma_f32_16x16x32_bf16(afr[1][1], b1, D1, 0, 0, 0);
        D1 = __builtin_amdgcn_mfma_f32_16x16x32_bf16(afr[1][2], b2, D1, 0, 0, 0);
        D1 = __builtin_amdgcn_mfma_f32_16x16x32_bf16(afr[1][3], b3, D1, 0, 0, 0);

        const float nmc = nmcA[ct];
        float cpE = 0.f, cpS = 0.f;
        #pragma unroll
        for (int r = 0; r < 4; ++r) {
            float d0 = D0[r], d1 = D1[r];
            float e0 = EXP2(d0), e1 = EXP2(d1);
            if (DIAG) {
                const int colg = C0 + ct * 16 + cq;
                const float ex0 = (rbase + r == colg) ? 0.f : 1.f;
                const float ex1 = (rbase + 16 + r == colg) ? 0.f : 1.f;
                e0 *= ex0; d0 *= ex0;
                e1 *= ex1; d1 *= ex1;
            }
            accE[0][r] += e0 * nmc;  cpE += e0 * nmR[0][r];
            accS[0][r] += d0 * nmc;  cpS += d0 * nmR[0][r];
            accE[1][r] += e1 * nmc;  cpE += e1 * nmR[1][r];
            accS[1][r] += d1 * nmc;  cpS += d1 * nmR[1][r];
        }
        cpE += __shfl_xor(cpE, 16); cpE += __shfl_xor(cpE, 32);
        cpS += __shfl_xor(cpS, 16); cpS += __shfl_xor(cpS, 32);
        if (quad == 0) {
            colE[wv][ct * 16 + cq] = cpE;
            colS[wv][ct * 16 + cq] = cpS;
        }

        b0 = t0; b1 = t1; b2 = t2; b3 = t3;
    }

    // row sums: reduce over the 16 cq lanes, write slot 2b+h
    #pragma unroll
    for (int mt = 0; mt < 2; ++mt)
        #pragma unroll
        for (int r = 0; r < 4; ++r) {
            float e = accE[mt][r], s = accS[mt][r];
            e += __shfl_xor(e, 1); e += __shfl_xor(e, 2);
            e += __shfl_xor(e, 4); e += __shfl_xor(e, 8);
            s += __shfl_xor(s, 1); s += __shfl_xor(s, 2);
            s += __shfl_xor(s, 4); s += __shfl_xor(s, 8);
            accE[mt][r] = e; accS[mt][r] = s;
        }
    if (cq == 0) {
        const size_t slotR = (size_t)(2 * b + h) * M_TOT;
        #pragma unroll
        for (int mt = 0; mt < 2; ++mt)
            #pragma unroll
            for (int r = 0; r < 4; ++r) {
                const int rowg = R0 + wv * 32 + mt * 16 + quad * 4 + r;
                rowE[slotR + rowg] = accE[mt][r];
                rowS[slotR + rowg] = accS[mt][r];
            }
    }

    __syncthreads();
    if (!DIAG) {
        const size_t slotC = (size_t)(2 * a + h) * M_TOT;
        const float ce = colE[0][tid] + colE[1][tid] + colE[2][tid] + colE[3][tid];
        const float cs = colS[0][tid] + colS[1][tid] + colS[2][tid] + colS[3][tid];
        rowE[slotC + C0 + tid] = ce;
        rowS[slotC + C0 + tid] = cs;
    }
}

// ---------------------------------------------------------------- k_sym
// 1056 blocks x 256 thr. Blocks 0..63: diagonal half-tiles (c = id>>1,
// h = id&1). Blocks 64..1055: strict-upper pairs (a<b), two halves each.
// Block 0 also reduces nfcnt -> NnOut.
__global__ __launch_bounds__(256, 2) void k_sym(
        const unsigned short* __restrict__ Fb, const unsigned short* __restrict__ Fc,
        const int* __restrict__ nf,
        float* __restrict__ rowE, float* __restrict__ rowS,
        const int* __restrict__ nfcnt, int* __restrict__ NnOut) {
    __shared__ float colE[4][256];
    __shared__ float colS[4][256];

    const int id = blockIdx.x;
    if (id < NDIAG) {
        const int c = id >> 1, h = id & 1;
        sym_body<true>(c, c, h, c * RT + h * 128, c * RT,
                       Fb, Fc, nf, rowE, rowS, colE, colS);
        if (id == 0) {
            const int tid = threadIdx.x;
            if (tid >= 64 && tid < 128) {
                const int l = tid - 64;
                int cs = 0;
                #pragma unroll
                for (int r = 0; r < 8; ++r) cs += nfcnt[l + 64 * r];
                for (int off = 1; off < 64; off <<= 1) cs += __shfl_xor(cs, off);
                if (l == 0) *NnOut = cs;
            }
        }
    } else {
        const int tp = id - NDIAG;
        const int p = tp >> 1, h = tp & 1;
        int aa = 0, rem = p;
        while (rem >= NT - 1 - aa) { rem -= (NT - 1 - aa); ++aa; }
        const int bb2 = aa + 1 + rem;
        sym_body<false>(aa, bb2, h, aa * RT + h * 128, bb2 * RT,
                        Fb, Fc, nf, rowE, rowS, colE, colS);
    }
}

// ---------------------------------------------------------------- k_final
// 512 blocks x 256 thr, 16 rows/block. Per row i: ep = sum of 64 rowE slots
// (= sum_{j novel, j!=i} exp(S_ij), diag excluded in-tile); sp = same for raw
// D; loss per reference formula.
__global__ __launch_bounds__(256) void k_final(
        const int* __restrict__ nf,
        const float* __restrict__ rowE, const float* __restrict__ rowS,
        const float* __restrict__ Psum, const float* __restrict__ expPsum,
        const float* __restrict__ PLab,
        const int* __restrict__ NnPtr,
        float* __restrict__ out) {
    __shared__ float sh[16];
    __shared__ int shNn;
    const int tid = threadIdx.x;

    if (tid == 0) shNn = *NnPtr;
    __syncthreads();

    const int rp = tid >> 4, u = tid & 15;
    const int i = blockIdx.x * 16 + rp;
    float ep = rowE[(size_t)u * M_TOT + i]
             + rowE[(size_t)(u + 16) * M_TOT + i]
             + rowE[(size_t)(u + 32) * M_TOT + i]
             + rowE[(size_t)(u + 48) * M_TOT + i];
    float sp = rowS[(size_t)u * M_TOT + i]
             + rowS[(size_t)(u + 16) * M_TOT + i]
             + rowS[(size_t)(u + 32) * M_TOT + i]
             + rowS[(size_t)(u + 48) * M_TOT + i];
    for (int off = 1; off < 16; off <<= 1) {
        ep += __shfl_xor(ep, off);
        sp += __shfl_xor(sp, off);
    }

    if (u == 0) {
        const int Nn = shNn;
        float contrib;
        if (nf[i]) {
            const float cnt = (float)(Nn - 1);
            const float denom = ep + Psum[i];        // + RAW proto logit sum (faithful)
            const float num = sp * LN2 - logf(denom) * cnt;
            const float sc = cnt > 0.f ? cnt : 1.f;
            contrib = -(num / sc);
        } else {
            contrib = -(PLab[i] - logf(ep + expPsum[i]));
        }
        sh[rp] = contrib;
    }
    __syncthreads();
    if (tid == 0) {
        float s = 0.f;
        #pragma unroll
        for (int r = 0; r < 16; ++r) s += sh[r];
        atomicAdd(out, s * (1.0f / (float)M_TOT));
    }
}

// ---------------------------------------------------------------- launch
extern "C" void kernel_launch(void* const* d_in, const int* in_sizes, int n_in,
                              void* d_out, int out_size, void* d_ws, size_t ws_size,
                              hipStream_t stream) {
    const float* feat    = (const float*)d_in[0];
    const int*   labels  = (const int*)d_in[1];
    const float* protos  = (const float*)d_in[2];
    const int*   plabels = (const int*)d_in[3];
    float* out = (float*)d_out;

    char* ws = (char*)d_ws;
    int*   nfcnt   = (int*)ws;                       // 512 ints
    int*   NnOut   = (int*)(ws + 4096);
    float* rowE    = (float*)(ws + 8192);            // 64 x 8192 fp32 (2 MB)
    float* rowS    = (float*)(ws + 8192 + 2097152);  // 64 x 8192 fp32 (2 MB)
    float* Psum    = (float*)(ws + 4202496);
    float* expPsum = (float*)(ws + 4235264);
    float* PLab    = (float*)(ws + 4268032);
    int*   nf      = (int*)(ws + 4300800);
    unsigned short* Fb = (unsigned short*)(ws + 4333568);            // 2 MB
    unsigned short* Fc = (unsigned short*)(ws + 4333568 + 2097152);  // 2 MB

    k_prep<<<M_TOT / 16, 256, 0, stream>>>(feat, labels, protos, plabels,
                                           Psum, expPsum, PLab, nf, nfcnt,
                                           Fb, Fc, rowE, rowS, out);
    k_sym<<<NBLK, 256, 0, stream>>>(Fb, Fc, nf, rowE, rowS, nfcnt, NnOut);
    k_final<<<M_TOT / 16, 256, 0, stream>>>(nf, rowE, rowS, Psum, expPsum, PLab,
                                            NnOut, out);
}

// Round 4
// 115.978 us; speedup vs baseline: 1.0819x; 1.0819x over previous
//
#include <hip/hip_runtime.h>
#include <stdint.h>

// SupConLossWithPrototype on MI355X.
// Round 15: total has been k_sym + ~78us constant for 3 rounds while k_prep /
// k_final were restructured -> the constant lives in the serial 3-kernel
// chain, with k_prep (full conversion pass) the prime suspect. This round
// deletes k_prep entirely:
//  - k_sym converts its own operands from f32 feat: A-fragments in registers,
//    B-tile staged to LDS bf16(C*f) in two 128-col phases (stride 136, 16B
//    aligned, 2-way-bank-free ds_read_b128). No Fb/Fc workspace at all.
//  - novelty masks from labels x plabels in-block; diag blocks emit
//    nfpart[64]; pair blocks zero complementary row-slots (no pre-zero pass).
//  - LDS ~45KB -> launch_bounds(256,3), 3 blocks/CU (was 2).
//  - k_final absorbs the proto MFMA (verbatim from k_prep) + Nn reduction.
// Math and FP order identical to round 14 (bit-identical expected).

#define M_TOT 8192
#define K_DIM 128
#define B_PRO 100
#define INV_T 5.0f                          // 1/TEMP
#define C_SCALE 7.2134752044448170f         // 5 * log2(e)
#define LN2    0.6931471805599453f
#define RT    256                           // k_sym tile side
#define NT    (M_TOT / RT)                  // 32 row/col groups
#define NDIAG (2 * NT)                      // 64 diagonal half-blocks
#define NPAIR (NT * (NT - 1) / 2)           // 496 strict upper pairs
#define NBLK  (NDIAG + 2 * NPAIR)           // 1056 blocks
#define BS    136                           // k_sym B LDS stride (bf16 elems)
#define PB    112                           // padded proto rows (7 groups of 16)
#define PS    136                           // proto LDS stride (bf16 elems)
#define FS    136                           // feat LDS stride

#if __has_builtin(__builtin_amdgcn_exp2f)
#define EXP2(x) __builtin_amdgcn_exp2f(x)
#else
#define EXP2(x) __expf((x) * 0.6931471805599453f)
#endif

typedef __attribute__((ext_vector_type(8))) short  short8;   // 8 bf16 (MFMA A/B frag)
typedef __attribute__((ext_vector_type(4))) float  floatx4;  // MFMA C/D frag

__device__ __forceinline__ float bf2f(unsigned short u) {
    union { unsigned int i; float f; } v; v.i = ((unsigned int)u) << 16; return v.f;
}
__device__ __forceinline__ unsigned short f2bf(float x) {   // RNE
    union { float f; unsigned int i; } v; v.f = x;
    return (unsigned short)((v.i + 0x7fffu + ((v.i >> 16) & 1u)) >> 16);
}
__device__ __forceinline__ float lo_bf(unsigned int u) {
    union { unsigned int i; float f; } v; v.i = u << 16; return v.f;
}
__device__ __forceinline__ float hi_bf(unsigned int u) {
    union { unsigned int i; float f; } v; v.i = u & 0xffff0000u; return v.f;
}
__device__ __forceinline__ short8 pack8(float4 a, float4 b, float sc) {
    short8 r;
    r[0] = (short)f2bf(a.x * sc); r[1] = (short)f2bf(a.y * sc);
    r[2] = (short)f2bf(a.z * sc); r[3] = (short)f2bf(a.w * sc);
    r[4] = (short)f2bf(b.x * sc); r[5] = (short)f2bf(b.y * sc);
    r[6] = (short)f2bf(b.z * sc); r[7] = (short)f2bf(b.w * sc);
    return r;
}

// ---------------------------------------------------------------- k_sym body
// One 128-row x 256-col half-tile, operands converted in-block from f32 feat.
// Dual accumulation: accE = sum exp2(D)*mask, accS = sum D*mask, row and col
// direction. DIAG excludes row==col exactly. Pair blocks also zero the
// complementary slot 2b+(1-h) for their rows; diag blocks likewise -> no
// workspace pre-zeroing needed anywhere.
template<bool DIAG>
__device__ __forceinline__ void sym_body(
        int a, int b, int h, int R0, int C0,
        const float* __restrict__ feat, const int* __restrict__ labels,
        const int* __restrict__ plabels,
        float* __restrict__ rowE, float* __restrict__ rowS,
        int* __restrict__ nfpart,
        unsigned short* ldsB, float (*colE)[256], float (*colS)[256],
        float* novR, float* novC, int* plabL) {
    const int tid = threadIdx.x;
    const int wv = tid >> 6, lane = tid & 63;
    const int quad = lane >> 4, cq = lane & 15;

    if (tid < B_PRO) plabL[tid] = plabels[tid];

    // A fragments straight from f32 feat, converted in registers:
    // rows R0 + wv*32 + mt*16 + cq, k = ks*32 + quad*8 .. +7
    short8 afr[2][4];
    #pragma unroll
    for (int mt = 0; mt < 2; ++mt)
        #pragma unroll
        for (int ks = 0; ks < 4; ++ks) {
            const float* s = feat + (size_t)(R0 + wv * 32 + mt * 16 + cq) * K_DIM
                             + ks * 32 + quad * 8;
            float4 x = ((const float4*)s)[0];
            float4 y = ((const float4*)s)[1];
            afr[mt][ks] = pack8(x, y, 1.0f);
        }
    __syncthreads();   // plabL visible

    // novelty for 128 rows + 256 cols from labels x plabels
    for (int e = tid; e < 384; e += 256) {
        const int g = (e < 128) ? (R0 + e) : (C0 + (e - 128));
        const int lbl = labels[g];
        int m = 0;
        for (int j = 0; j < B_PRO; ++j) m |= (plabL[j] == lbl);
        const float nv = m ? 0.f : 1.f;
        if (e < 128) novR[e] = nv; else novC[e - 128] = nv;
    }
    __syncthreads();   // novR/novC visible

    float nmR[2][4];
    #pragma unroll
    for (int mt = 0; mt < 2; ++mt)
        #pragma unroll
        for (int r = 0; r < 4; ++r)
            nmR[mt][r] = novR[wv * 32 + mt * 16 + quad * 4 + r];
    float nmcA[16];
    #pragma unroll
    for (int c2 = 0; c2 < 16; ++c2)
        nmcA[c2] = novC[c2 * 16 + cq];

    float accE[2][4], accS[2][4];
    #pragma unroll
    for (int mt = 0; mt < 2; ++mt)
        #pragma unroll
        for (int r = 0; r < 4; ++r) { accE[mt][r] = 0.f; accS[mt][r] = 0.f; }

    const int rbase = R0 + wv * 32 + quad * 4;   // DIAG row index helper

    #pragma unroll 1
    for (int half = 0; half < 2; ++half) {
        // stage cols [C0 + half*128, +128) as bf16(C*f) into LDS
        for (int e = tid; e < 2048; e += 256) {
            const int col = e >> 4, sg = e & 15;
            const float* s = feat + (size_t)(C0 + half * 128 + col) * K_DIM + sg * 8;
            float4 x = ((const float4*)s)[0];
            float4 y = ((const float4*)s)[1];
            ushort4 o0 = make_ushort4(f2bf(x.x*C_SCALE), f2bf(x.y*C_SCALE),
                                      f2bf(x.z*C_SCALE), f2bf(x.w*C_SCALE));
            ushort4 o1 = make_ushort4(f2bf(y.x*C_SCALE), f2bf(y.y*C_SCALE),
                                      f2bf(y.z*C_SCALE), f2bf(y.w*C_SCALE));
            *(ushort4*)&ldsB[col * BS + sg * 8]     = o0;
            *(ushort4*)&ldsB[col * BS + sg * 8 + 4] = o1;
        }
        __syncthreads();   // staging visible

        #pragma unroll 2
        for (int ct8 = 0; ct8 < 8; ++ct8) {
            const int ct = half * 8 + ct8;
            const unsigned short* bp = &ldsB[(ct8 * 16 + cq) * BS + quad * 8];
            short8 b0 = *(const short8*)(bp);
            short8 b1 = *(const short8*)(bp + 32);
            short8 b2 = *(const short8*)(bp + 64);
            short8 b3 = *(const short8*)(bp + 96);

            floatx4 D0 = (floatx4){0.f, 0.f, 0.f, 0.f};
            floatx4 D1 = (floatx4){0.f, 0.f, 0.f, 0.f};
            D0 = __builtin_amdgcn_mfma_f32_16x16x32_bf16(afr[0][0], b0, D0, 0, 0, 0);
            D0 = __builtin_amdgcn_mfma_f32_16x16x32_bf16(afr[0][1], b1, D0, 0, 0, 0);
            D0 = __builtin_amdgcn_mfma_f32_16x16x32_bf16(afr[0][2], b2, D0, 0, 0, 0);
            D0 = __builtin_amdgcn_mfma_f32_16x16x32_bf16(afr[0][3], b3, D0, 0, 0, 0);
            D1 = __builtin_amdgcn_mfma_f32_16x16x32_bf16(afr[1][0], b0, D1, 0, 0, 0);
            D1 = __builtin_amdgcn_mfma_f32_16x16x32_bf16(afr[1][1], b1, D1, 0, 0, 0);
            D1 = __builtin_amdgcn_mfma_f32_16x16x32_bf16(afr[1][2], b2, D1, 0, 0, 0);
            D1 = __builtin_amdgcn_mfma_f32_16x16x32_bf16(afr[1][3], b3, D1, 0, 0, 0);

            const float nmc = nmcA[ct];
            float cpE = 0.f, cpS = 0.f;
            #pragma unroll
            for (int r = 0; r < 4; ++r) {
                float d0 = D0[r], d1 = D1[r];
                float e0 = EXP2(d0), e1 = EXP2(d1);
                if (DIAG) {
                    const int colg = C0 + ct * 16 + cq;
                    const float ex0 = (rbase + r == colg) ? 0.f : 1.f;
                    const float ex1 = (rbase + 16 + r == colg) ? 0.f : 1.f;
                    e0 *= ex0; d0 *= ex0;
                    e1 *= ex1; d1 *= ex1;
                }
                accE[0][r] += e0 * nmc;  cpE += e0 * nmR[0][r];
                accS[0][r] += d0 * nmc;  cpS += d0 * nmR[0][r];
                accE[1][r] += e1 * nmc;  cpE += e1 * nmR[1][r];
                accS[1][r] += d1 * nmc;  cpS += d1 * nmR[1][r];
            }
            cpE += __shfl_xor(cpE, 16); cpE += __shfl_xor(cpE, 32);
            cpS += __shfl_xor(cpS, 16); cpS += __shfl_xor(cpS, 32);
            if (quad == 0) {
                colE[wv][ct * 16 + cq] = cpE;
                colS[wv][ct * 16 + cq] = cpS;
            }
        }
        __syncthreads();   // reads done before restage; end publishes colE/colS
    }

    // row sums: reduce over the 16 cq lanes, write slot 2b+h
    #pragma unroll
    for (int mt = 0; mt < 2; ++mt)
        #pragma unroll
        for (int r = 0; r < 4; ++r) {
            float e = accE[mt][r], s = accS[mt][r];
            e += __shfl_xor(e, 1); e += __shfl_xor(e, 2);
            e += __shfl_xor(e, 4); e += __shfl_xor(e, 8);
            s += __shfl_xor(s, 1); s += __shfl_xor(s, 2);
            s += __shfl_xor(s, 4); s += __shfl_xor(s, 8);
            accE[mt][r] = e; accS[mt][r] = s;
        }
    if (cq == 0) {
        const size_t slotR = (size_t)(2 * b + h) * M_TOT;
        #pragma unroll
        for (int mt = 0; mt < 2; ++mt)
            #pragma unroll
            for (int r = 0; r < 4; ++r) {
                const int rowg = R0 + wv * 32 + mt * 16 + quad * 4 + r;
                rowE[slotR + rowg] = accE[mt][r];
                rowS[slotR + rowg] = accS[mt][r];
            }
    }
    // complementary slot for our rows is written by nobody -> zero it here
    {
        const size_t slotZ = (size_t)(2 * b + (1 - h)) * M_TOT;
        if (tid < 128) {
            rowE[slotZ + R0 + tid] = 0.f;
            rowS[slotZ + R0 + tid] = 0.f;
        }
    }

    if (!DIAG) {
        const float ce = colE[0][tid] + colE[1][tid] + colE[2][tid] + colE[3][tid];
        const float cs = colS[0][tid] + colS[1][tid] + colS[2][tid] + colS[3][tid];
        const size_t slotC = (size_t)(2 * a + h) * M_TOT;
        rowE[slotC + C0 + tid] = ce;
        rowS[slotC + C0 + tid] = cs;
    } else {
        if (tid == 0) {
            float c = 0.f;
            #pragma unroll
            for (int r = 0; r < 128; ++r) c += novR[r];
            nfpart[2 * a + h] = (int)c;
        }
    }
}

// ---------------------------------------------------------------- k_sym
// 1056 blocks x 256 thr. Blocks 0..63: diagonal half-tiles (c = id>>1,
// h = id&1). Blocks 64..1055: strict-upper pairs (a<b), two halves each.
// Block 0 zeroes out[0] (k_final accumulates after).
__global__ __launch_bounds__(256, 3) void k_sym(
        const float* __restrict__ feat, const int* __restrict__ labels,
        const int* __restrict__ plabels,
        float* __restrict__ rowE, float* __restrict__ rowS,
        int* __restrict__ nfpart, float* __restrict__ out) {
    __shared__ unsigned short ldsB[128 * BS];    // 34816 B
    __shared__ float colE[4][256];               // 4096 B
    __shared__ float colS[4][256];               // 4096 B
    __shared__ float novR[128];                  // 512 B
    __shared__ float novC[256];                  // 1024 B
    __shared__ int plabL[B_PRO];                 // 400 B

    if (blockIdx.x == 0 && threadIdx.x == 0) out[0] = 0.f;

    const int id = blockIdx.x;
    if (id < NDIAG) {
        const int c = id >> 1, h = id & 1;
        sym_body<true>(c, c, h, c * RT + h * 128, c * RT,
                       feat, labels, plabels, rowE, rowS, nfpart,
                       ldsB, colE, colS, novR, novC, plabL);
    } else {
        const int tp = id - NDIAG;
        const int p = tp >> 1, h = tp & 1;
        int aa = 0, rem = p;
        while (rem >= NT - 1 - aa) { rem -= (NT - 1 - aa); ++aa; }
        const int bb2 = aa + 1 + rem;
        sym_body<false>(aa, bb2, h, aa * RT + h * 128, bb2 * RT,
                        feat, labels, plabels, rowE, rowS, nfpart,
                        ldsB, colE, colS, novR, novC, plabL);
    }
}

// ---------------------------------------------------------------- k_final
// 512 blocks x 256 thr, 16 rows/block. Absorbs the old k_prep proto GEMM:
// stages protos (zero-padded to 112) + 16 feat rows as bf16 in LDS, computes
// P = feat.protos^T/T via MFMA -> Psum/expPsum/PLab in LDS; novelty per row
// from labels x plabels; Nn from nfpart[64]; then slot-sums rowE/rowS and
// emits the loss contribution.
__global__ __launch_bounds__(256) void k_final(
        const float* __restrict__ feat, const int* __restrict__ labels,
        const float* __restrict__ protos, const int* __restrict__ plabels,
        const float* __restrict__ rowE, const float* __restrict__ rowS,
        const int* __restrict__ nfpart,
        float* __restrict__ out) {
    __shared__ unsigned short protoB[PB * PS];   // 30464 B
    __shared__ unsigned short featB[16 * FS];    // 4352 B
    __shared__ float psW[4][16], esW[4][16], plW[4][16];
    __shared__ float PsL[16], esL[16], plL[16];
    __shared__ float sh[16];
    __shared__ int labL[16];
    __shared__ int plabL[B_PRO];
    __shared__ int novL[16];
    __shared__ int shNn;

    const int tid = threadIdx.x;
    const int rowBase = blockIdx.x * 16;

    if (tid < B_PRO) plabL[tid] = plabels[tid];
    if (tid >= 128 && tid < 144) labL[tid - 128] = labels[rowBase + tid - 128];

    // stage protos -> bf16 LDS (3200 float4s strided over 256 threads)
    for (int idx = tid; idx < 3200; idx += 256) {
        const int pr = idx >> 5, sg = idx & 31;
        float4 v = ((const float4*)protos)[idx];
        *(ushort4*)&protoB[pr * PS + sg * 4] =
            make_ushort4(f2bf(v.x), f2bf(v.y), f2bf(v.z), f2bf(v.w));
    }
    for (int idx = tid; idx < 12 * 32; idx += 256) {   // zero-pad rows 100..111
        const int pr = B_PRO + (idx >> 5), sg = idx & 31;
        *(ushort4*)&protoB[pr * PS + sg * 4] = make_ushort4(0, 0, 0, 0);
    }

    // stage this thread's feat segment (row rp, cols pq*8..+7) -> LDS
    const int rp = tid >> 4, pq = tid & 15;
    {
        const float* src = feat + (size_t)(rowBase + rp) * K_DIM + pq * 8;
        float4 fa  = ((const float4*)src)[0];
        float4 fb4 = ((const float4*)src)[1];
        *(ushort4*)&featB[rp * FS + pq * 8] =
            make_ushort4(f2bf(fa.x), f2bf(fa.y), f2bf(fa.z), f2bf(fa.w));
        *(ushort4*)&featB[rp * FS + pq * 8 + 4] =
            make_ushort4(f2bf(fb4.x), f2bf(fb4.y), f2bf(fb4.z), f2bf(fb4.w));
    }
    __syncthreads();

    // novelty per row
    const int lbl = labL[rp];
    float flg = 0.f;
    #pragma unroll
    for (int j = 0; j < 7; ++j) {
        const int jj = pq + 16 * j;
        if (jj < B_PRO && plabL[jj] == lbl) flg = 1.f;
    }
    for (int off = 1; off < 16; off <<= 1) flg += __shfl_xor(flg, off);
    if (pq == 0) novL[rp] = (flg == 0.f) ? 1 : 0;

    // Nn from nfpart partials
    if (tid < 64) {
        int c = nfpart[tid];
        for (int off = 1; off < 64; off <<= 1) c += __shfl_xor(c, off);
        if (tid == 0) shNn = c;
    }

    // proto GEMM via MFMA: wave w handles col-group w (and w+4 if w<3)
    const int wv = tid >> 6, lane = tid & 63, quad = lane >> 4, cq = lane & 15;
    short8 af[4];
    #pragma unroll
    for (int ks = 0; ks < 4; ++ks)
        af[ks] = *(const short8*)&featB[cq * FS + ks * 32 + quad * 8];

    float ps_[4] = {0.f, 0.f, 0.f, 0.f};
    float es_[4] = {0.f, 0.f, 0.f, 0.f};
    float pl_[4] = {0.f, 0.f, 0.f, 0.f};

    #pragma unroll
    for (int gi = 0; gi < 2; ++gi) {
        const int g = wv + 4 * gi;
        if (gi == 1 && wv >= 3) break;     // groups 0..6 only
        short8 bf[4];
        #pragma unroll
        for (int ks = 0; ks < 4; ++ks)
            bf[ks] = *(const short8*)&protoB[(g * 16 + cq) * PS + ks * 32 + quad * 8];
        floatx4 D = (floatx4){0.f, 0.f, 0.f, 0.f};
        D = __builtin_amdgcn_mfma_f32_16x16x32_bf16(af[0], bf[0], D, 0, 0, 0);
        D = __builtin_amdgcn_mfma_f32_16x16x32_bf16(af[1], bf[1], D, 0, 0, 0);
        D = __builtin_amdgcn_mfma_f32_16x16x32_bf16(af[2], bf[2], D, 0, 0, 0);
        D = __builtin_amdgcn_mfma_f32_16x16x32_bf16(af[3], bf[3], D, 0, 0, 0);
        #pragma unroll
        for (int r = 0; r < 4; ++r) {
            const int bcol = g * 16 + cq;
            if (bcol < B_PRO) {
                const float Pv = D[r] * INV_T;
                ps_[r] += Pv;
                es_[r] += __expf(Pv);
                if (bcol == labL[quad * 4 + r]) pl_[r] += Pv;
            }
        }
    }
    #pragma unroll
    for (int r = 0; r < 4; ++r) {
        for (int off = 1; off < 16; off <<= 1) {
            ps_[r] += __shfl_xor(ps_[r], off);
            es_[r] += __shfl_xor(es_[r], off);
            pl_[r] += __shfl_xor(pl_[r], off);
        }
        if (cq == 0) {
            psW[wv][quad * 4 + r] = ps_[r];
            esW[wv][quad * 4 + r] = es_[r];
            plW[wv][quad * 4 + r] = pl_[r];
        }
    }

    // slot sums from rowE/rowS (independent of LDS state)
    const int i = rowBase + rp;
    float ep = rowE[(size_t)pq * M_TOT + i]
             + rowE[(size_t)(pq + 16) * M_TOT + i]
             + rowE[(size_t)(pq + 32) * M_TOT + i]
             + rowE[(size_t)(pq + 48) * M_TOT + i];
    float sp = rowS[(size_t)pq * M_TOT + i]
             + rowS[(size_t)(pq + 16) * M_TOT + i]
             + rowS[(size_t)(pq + 32) * M_TOT + i]
             + rowS[(size_t)(pq + 48) * M_TOT + i];
    for (int off = 1; off < 16; off <<= 1) {
        ep += __shfl_xor(ep, off);
        sp += __shfl_xor(sp, off);
    }

    __syncthreads();   // psW/esW/plW, novL, shNn all visible
    if (tid < 16) {
        PsL[tid] = psW[0][tid] + psW[1][tid] + psW[2][tid] + psW[3][tid];
        esL[tid] = esW[0][tid] + esW[1][tid] + esW[2][tid] + esW[3][tid];
        plL[tid] = plW[0][tid] + plW[1][tid] + plW[2][tid] + plW[3][tid];
    }
    __syncthreads();

    if (pq == 0) {
        const int Nn = shNn;
        float contrib;
        if (novL[rp]) {
            const float cnt = (float)(Nn - 1);
            const float denom = ep + PsL[rp];        // + RAW proto logit sum (faithful)
            const float num = sp * LN2 - logf(denom) * cnt;
            const float sc = cnt > 0.f ? cnt : 1.f;
            contrib = -(num / sc);
        } else {
            contrib = -(plL[rp] - logf(ep + esL[rp]));
        }
        sh[rp] = contrib;
    }
    __syncthreads();
    if (tid == 0) {
        float s = 0.f;
        #pragma unroll
        for (int r = 0; r < 16; ++r) s += sh[r];
        atomicAdd(out, s * (1.0f / (float)M_TOT));
    }
}

// ---------------------------------------------------------------- launch
extern "C" void kernel_launch(void* const* d_in, const int* in_sizes, int n_in,
                              void* d_out, int out_size, void* d_ws, size_t ws_size,
                              hipStream_t stream) {
    const float* feat    = (const float*)d_in[0];
    const int*   labels  = (const int*)d_in[1];
    const float* protos  = (const float*)d_in[2];
    const int*   plabels = (const int*)d_in[3];
    float* out = (float*)d_out;

    char* ws = (char*)d_ws;
    float* rowE   = (float*)ws;                      // 64 x 8192 fp32 (2 MB)
    float* rowS   = (float*)(ws + 2097152);          // 64 x 8192 fp32 (2 MB)
    int*   nfpart = (int*)(ws + 4194304);            // 64 ints

    k_sym<<<NBLK, 256, 0, stream>>>(feat, labels, plabels, rowE, rowS,
                                    nfpart, out);
    k_final<<<M_TOT / 16, 256, 0, stream>>>(feat, labels, protos, plabels,
                                            rowE, rowS, nfpart, out);
}